// Round 17
// baseline (25.246 us; speedup 1.0000x reference)
//
#include <hip/hip_runtime.h>

#define N_NODES 207
#define N_EDGES 1722
#define N_SLOTS 288
#define L_DIM 24            // 2*12 feature channels
#define NPK 12              // f16x2 words per node row (24 ch, 48 B)
#define TOT_ENT (2 * N_EDGES)   // 3444
#define THREADS 512         // 2 samples per block, 256 threads each
#define N_HELP 48           // helpers: threads 208-255 split top-48 nodes

typedef float f32x2 __attribute__((ext_vector_type(2)));
typedef __fp16 h16x2 __attribute__((ext_vector_type(2)));

__device__ __forceinline__ unsigned pkrtz(float a, float b) {
    h16x2 h = __builtin_amdgcn_cvt_pkrtz(a, b);
    return __builtin_bit_cast(unsigned, h);
}
__device__ __forceinline__ f32x2 h2f(unsigned u) {
    h16x2 h = __builtin_bit_cast(h16x2, u);
    f32x2 r; r.x = (float)h.x; r.y = (float)h.y;
    return r;
}
// acc(f16x2) += {wr,wr} * x ; wr = lo16 of wt (op_sel lo-broadcast).
__device__ __forceinline__ void fma_lo(unsigned& acc, unsigned wt, unsigned x) {
    asm("v_pk_fma_f16 %0, %1, %2, %0 op_sel:[0,0,0] op_sel_hi:[0,1,1]"
        : "+v"(acc) : "v"(wt), "v"(x));
}
// acc(f16x2) += {wd,wd} * x ; wd = hi16 of wt.
__device__ __forceinline__ void fma_hi(unsigned& acc, unsigned wt, unsigned x) {
    asm("v_pk_fma_f16 %0, %1, %2, %0 op_sel:[1,0,0] op_sel_hi:[1,1,1]"
        : "+v"(acc) : "v"(wt), "v"(x));
}
__device__ __forceinline__ void addw(unsigned& sw, unsigned wt) {
    asm("v_pk_add_f16 %0, %1, %0" : "+v"(sw) : "v"(wt));
}
// fast tanh: 1 - 2/(e^{2x}+1); both saturation limits exact.
__device__ __forceinline__ float fast_tanhf(float x) {
    float e2 = __expf(2.0f * x);
    return 1.0f - 2.0f * __builtin_amdgcn_rcpf(e2 + 1.0f);
}

// ---------------------------------------------------------------------------
// Single fused kernel, 512 blocks x 512 threads, 2 samples per block
// (waves 0-3 -> sample A, waves 4-7 -> sample B). One shared CSR build;
// fused per-half {nbr, wt} b64 entry stream; all global loads issued at
// kernel top in consumption order.
// R17: threads 208-255 are HELPERS — node perm[k] (k<48, highest degree)
// is split: owner k gathers [beg, mid), helper 208+k gathers [mid, end).
// Post-loop: owners pull own x-row to regs; helpers dump 25-word partials
// over the dead x_sh region; owners k<48 merge with pk_add_f16. Wave trip
// counts drop from {28,20,17,15} to {~20,~18,~16,~14}.
// ---------------------------------------------------------------------------
__global__ __launch_bounds__(THREADS, 4) void rdgcn_fused_kernel(
    const float* __restrict__ x_in,      // [B, 24, 207]
    const float* __restrict__ w_react,   // [N_SLOTS, N_EDGES]
    const float* __restrict__ w_diff,    // [N_SLOTS, N_EDGES]
    const float* __restrict__ b_react,   // [N_SLOTS, N_NODES]
    const float* __restrict__ b_diff,    // [N_SLOTS, N_NODES]
    const float* __restrict__ w_self,    // [N_SLOTS, N_NODES]
    const int* __restrict__ ind,         // [B]
    const int* __restrict__ edge_index,  // [2, N_EDGES]
    float* __restrict__ out)             // [B, 207, 24]
{
    __shared__ unsigned x_sh[2][N_NODES * NPK];   // 19872 B (scratch + partials alias)
    __shared__ uint2    ewt_sh[2][TOT_ENT];       // 55104 B  (total 74976 B)

    const int tid  = threadIdx.x;
    const int h    = tid >> 8;          // sample half within block
    const int htid = tid & 255;
    const int lane = tid & 63;
    const int wid  = tid >> 6;
    const int bA   = blockIdx.x * 2;
    const int b    = bA + h;            // this thread's sample
    const int sA   = ind[bA];
    const int sB   = ind[bA + 1];
    const int s    = h ? sB : sA;

    const bool is_owner  = (htid < N_NODES);
    const bool is_helper = (htid >= 208);

    // ---- issue ALL global loads at top, in consumption order ----
    int ei[4], ej[4];
    int ne = 0;
    #pragma unroll
    for (int q = 0; q < 4; ++q) {
        const int e = tid + q * THREADS;
        if (e < N_EDGES) {
            ei[q] = edge_index[e];
            ej[q] = edge_index[N_EDGES + e];
            ne = q + 1;
        }
    }
    float wAr[4], wAd[4], wBr[4], wBd[4];
    {
        const float* wrgA = w_react + (size_t)sA * N_EDGES;
        const float* wdgA = w_diff  + (size_t)sA * N_EDGES;
        const float* wrgB = w_react + (size_t)sB * N_EDGES;
        const float* wdgB = w_diff  + (size_t)sB * N_EDGES;
        #pragma unroll
        for (int q = 0; q < 4; ++q) {
            const int e = tid + q * THREADS;
            if (e < N_EDGES) {
                wAr[q] = wrgA[e]; wAd[q] = wdgA[e];
                wBr[q] = wrgB[e]; wBd[q] = wdgB[e];
            }
        }
    }
    float r[L_DIM];
    if (is_owner) {
        const float* xg = x_in + (size_t)b * (L_DIM * N_NODES);
        #pragma unroll
        for (int l = 0; l < L_DIM; ++l) r[l] = xg[l * N_NODES + htid];
    }

    // ---- build scratch aliased over x_sh (901 ints < 4968 available) ----
    int* cnt_s  = (int*)x_sh;           // [208]
    int* cur_s  = cnt_s + 208;          // [208]
    int* off_s  = cur_s + 208;          // [209]
    int* perm_s = off_s + 209;          // [208]
    int* dcur_s = perm_s + 208;         // [64]
    int* wsum_s = dcur_s + 64;          // [4]

    if (tid < 208) cnt_s[tid] = 0;
    if (tid < 64)  dcur_s[tid] = 0;
    __syncthreads();

    for (int q = 0; q < ne; ++q) {
        atomicAdd(&cnt_s[ei[q]], 1);
        atomicAdd(&cnt_s[ej[q]], 1);
    }
    __syncthreads();

    const int deg  = (tid < N_NODES) ? cnt_s[tid] : 0;
    const int dcap = deg > 63 ? 63 : deg;
    int xs = deg;
    if (tid < 256) {
        #pragma unroll
        for (int sft = 1; sft < 64; sft <<= 1) {
            int t = __shfl_up(xs, sft, 64);
            if (lane >= sft) xs += t;
        }
        if (lane == 63) wsum_s[wid] = xs;
    }
    if (tid < N_NODES) atomicAdd(&dcur_s[dcap], 1);
    __syncthreads();

    int base = 0;
    if (tid < 256) { for (int i = 0; i < wid; ++i) base += wsum_s[i]; }
    const int excl = base + xs - deg;
    if (tid < N_NODES) { off_s[tid] = excl; cur_s[tid] = excl; }
    if (tid == 255)    off_s[N_NODES] = base + xs;

    if (tid < 64) {
        int hg = dcur_s[63 - tid];
        int ys = hg;
        #pragma unroll
        for (int sft = 1; sft < 64; sft <<= 1) {
            int t = __shfl_up(ys, sft, 64);
            if (lane >= sft) ys += t;
        }
        __syncthreads();                 // all reads of dcur done
        dcur_s[63 - tid] = ys - hg;
    } else {
        __syncthreads();
    }
    __syncthreads();

    if (tid < N_NODES) {
        int p = atomicAdd(&dcur_s[dcap], 1);
        perm_s[p] = tid;
    }
    // pass 2: place entries with both halves' packed weights
    for (int q = 0; q < ne; ++q) {
        const unsigned wtA = pkrtz(wAr[q], wAd[q]);
        const unsigned wtB = pkrtz(wBr[q], wBd[q]);
        const int i = ei[q], j = ej[q];
        int pi = atomicAdd(&cur_s[i], 1);
        ewt_sh[0][pi] = make_uint2((unsigned)j, wtA);
        ewt_sh[1][pi] = make_uint2((unsigned)j, wtB);
        int pj = atomicAdd(&cur_s[j], 1);
        ewt_sh[0][pj] = make_uint2((unsigned)i, wtA);
        ewt_sh[1][pj] = make_uint2((unsigned)i, wtB);
    }
    __syncthreads();

    // consume scratch into registers before x staging overwrites it.
    // Owners k < N_HELP keep only the first (ceil) half of their range;
    // helper 208+k takes the tail half of node perm[k].
    int w = 0, beg = 0, end = 0;
    if (is_owner) {
        w   = perm_s[htid];
        beg = off_s[w];
        end = off_s[w + 1];
        if (htid < N_HELP) end = beg + ((end - beg + 1) >> 1);
    } else if (is_helper) {
        const int k = htid - 208;
        const int wn = perm_s[k];
        const int b0 = off_s[wn], e0 = off_s[wn + 1];
        beg = b0 + ((e0 - b0 + 1) >> 1);
        end = e0;
    }
    __syncthreads();   // scratch reads complete; x_sh region free

    float br = 0.f, bd = 0.f, wsl = 0.f;
    if (is_owner) {
        br  = b_react[s * N_NODES + w];
        bd  = b_diff [s * N_NODES + w];
        wsl = w_self [s * N_NODES + w];
        unsigned p[NPK];
        #pragma unroll
        for (int i = 0; i < NPK; ++i) p[i] = pkrtz(r[2*i], r[2*i+1]);
        uint4* dst = reinterpret_cast<uint4*>(&x_sh[h][htid * NPK]);
        dst[0] = make_uint4(p[0], p[1], p[2],  p[3]);
        dst[1] = make_uint4(p[4], p[5], p[6],  p[7]);
        dst[2] = make_uint4(p[8], p[9], p[10], p[11]);
    }
    __syncthreads();

    unsigned accr[NPK] = {0,0,0,0,0,0,0,0,0,0,0,0};   // f16x2 (reaction)
    unsigned accd[NPK] = {0,0,0,0,0,0,0,0,0,0,0,0};   // f16x2 (diffusion)
    unsigned sw = 0;                    // f16x2 (d_r, d_d) degree sums

    const uint2*    ew  = ewt_sh[h];
    const unsigned* xsh = x_sh[h];
    for (int k = beg; k < end; ++k) {
        const uint2 q = ew[k];          // sequential b64: {nbr, wt}
        const unsigned wt = q.y;
        const uint4* xr = reinterpret_cast<const uint4*>(&xsh[q.x * NPK]);
        const uint4 qa = xr[0], qb = xr[1], qc = xr[2];
        addw(sw, wt);
        fma_lo(accr[0],  wt, qa.x);   fma_hi(accd[0],  wt, qa.x);
        fma_lo(accr[1],  wt, qa.y);   fma_hi(accd[1],  wt, qa.y);
        fma_lo(accr[2],  wt, qa.z);   fma_hi(accd[2],  wt, qa.z);
        fma_lo(accr[3],  wt, qa.w);   fma_hi(accd[3],  wt, qa.w);
        fma_lo(accr[4],  wt, qb.x);   fma_hi(accd[4],  wt, qb.x);
        fma_lo(accr[5],  wt, qb.y);   fma_hi(accd[5],  wt, qb.y);
        fma_lo(accr[6],  wt, qb.z);   fma_hi(accd[6],  wt, qb.z);
        fma_lo(accr[7],  wt, qb.w);   fma_hi(accd[7],  wt, qb.w);
        fma_lo(accr[8],  wt, qc.x);   fma_hi(accd[8],  wt, qc.x);
        fma_lo(accr[9],  wt, qc.y);   fma_hi(accd[9],  wt, qc.y);
        fma_lo(accr[10], wt, qc.z);   fma_hi(accd[10], wt, qc.z);
        fma_lo(accr[11], wt, qc.w);   fma_hi(accd[11], wt, qc.w);
    }

    // ---- owners extract own x-row BEFORE partials overwrite x_sh ----
    unsigned own[NPK];
    if (is_owner) {
        const uint4* xw = reinterpret_cast<const uint4*>(&xsh[w * NPK]);
        const uint4 r0 = xw[0], r1 = xw[1], r2 = xw[2];
        own[0] = r0.x; own[1]  = r0.y; own[2]  = r0.z; own[3]  = r0.w;
        own[4] = r1.x; own[5]  = r1.y; own[6]  = r1.z; own[7]  = r1.w;
        own[8] = r2.x; own[9]  = r2.y; own[10] = r2.z; own[11] = r2.w;
    }
    __syncthreads();

    // ---- helpers dump partials into the dead x_sh region ----
    unsigned* part = (unsigned*)x_sh;   // flat; needs 2*48*25 = 2400 words
    if (is_helper) {
        const int k = htid - 208;
        unsigned* pp = part + (h * N_HELP + k) * 25;
        #pragma unroll
        for (int i = 0; i < NPK; ++i) { pp[i] = accr[i]; pp[NPK + i] = accd[i]; }
        pp[24] = sw;
    }
    __syncthreads();

    if (!is_owner) return;

    if (htid < N_HELP) {
        const unsigned* pp = part + (h * N_HELP + htid) * 25;
        #pragma unroll
        for (int i = 0; i < NPK; ++i) { addw(accr[i], pp[i]); addw(accd[i], pp[NPK + i]); }
        addw(sw, pp[24]);
    }

    const f32x2 sw2 = h2f(sw);
    const float swr = sw2.x, swd = sw2.y;

    float o[L_DIM];
    #pragma unroll
    for (int i = 0; i < NPK; ++i) {
        const f32x2 xv = h2f(own[i]);
        const f32x2 ar = h2f(accr[i]);
        const f32x2 ad = h2f(accd[i]);
        {
            float re = fmaf(swr, xv.x,  ar.x) + br;
            float di = fmaf(swd, xv.x, -ad.x) + bd;
            o[2*i]   = fast_tanhf(re) + di + fmaf(xv.x, wsl, xv.x);
        }
        {
            float re = fmaf(swr, xv.y,  ar.y) + br;
            float di = fmaf(swd, xv.y, -ad.y) + bd;
            o[2*i+1] = fast_tanhf(re) + di + fmaf(xv.y, wsl, xv.y);
        }
    }
    float* op = out + (size_t)b * (N_NODES * L_DIM) + (size_t)w * L_DIM;
    reinterpret_cast<float4*>(op)[0] = make_float4(o[0],  o[1],  o[2],  o[3]);
    reinterpret_cast<float4*>(op)[1] = make_float4(o[4],  o[5],  o[6],  o[7]);
    reinterpret_cast<float4*>(op)[2] = make_float4(o[8],  o[9],  o[10], o[11]);
    reinterpret_cast<float4*>(op)[3] = make_float4(o[12], o[13], o[14], o[15]);
    reinterpret_cast<float4*>(op)[4] = make_float4(o[16], o[17], o[18], o[19]);
    reinterpret_cast<float4*>(op)[5] = make_float4(o[20], o[21], o[22], o[23]);
}

extern "C" void kernel_launch(void* const* d_in, const int* in_sizes, int n_in,
                              void* d_out, int out_size, void* d_ws, size_t ws_size,
                              hipStream_t stream) {
    const float* x_in     = (const float*)d_in[0];
    const float* w_react  = (const float*)d_in[1];
    const float* w_diff   = (const float*)d_in[2];
    const float* b_react  = (const float*)d_in[3];
    const float* b_diff   = (const float*)d_in[4];
    const float* w_self   = (const float*)d_in[5];
    const int*   ind      = (const int*)d_in[6];
    const int*   edge_idx = (const int*)d_in[7];
    float* out = (float*)d_out;

    const int B = in_sizes[6];   // 1024
    rdgcn_fused_kernel<<<B / 2, THREADS, 0, stream>>>(x_in, w_react, w_diff,
                                                      b_react, b_diff, w_self,
                                                      ind, edge_idx, out);
}

// Round 18
// 24.391 us; speedup vs baseline: 1.0351x; 1.0351x over previous
//
#include <hip/hip_runtime.h>

#define N_NODES 207
#define N_EDGES 1722
#define N_SLOTS 288
#define L_DIM 24            // 2*12 feature channels
#define NPK 12              // f16x2 words per node row (24 ch, 48 B)
#define TOT_ENT (2 * N_EDGES)   // 3444
#define THREADS 512         // 2 samples per block, 256 threads each

typedef float f32x2 __attribute__((ext_vector_type(2)));
typedef __fp16 h16x2 __attribute__((ext_vector_type(2)));

__device__ __forceinline__ unsigned pkrtz(float a, float b) {
    h16x2 h = __builtin_amdgcn_cvt_pkrtz(a, b);
    return __builtin_bit_cast(unsigned, h);
}
__device__ __forceinline__ f32x2 h2f(unsigned u) {
    h16x2 h = __builtin_bit_cast(h16x2, u);
    f32x2 r; r.x = (float)h.x; r.y = (float)h.y;
    return r;
}
// acc(f16x2) += {wr,wr} * x ; wr = lo16 of wt (op_sel lo-broadcast).
__device__ __forceinline__ void fma_lo(unsigned& acc, unsigned wt, unsigned x) {
    asm("v_pk_fma_f16 %0, %1, %2, %0 op_sel:[0,0,0] op_sel_hi:[0,1,1]"
        : "+v"(acc) : "v"(wt), "v"(x));
}
// acc(f16x2) += {wd,wd} * x ; wd = hi16 of wt.
__device__ __forceinline__ void fma_hi(unsigned& acc, unsigned wt, unsigned x) {
    asm("v_pk_fma_f16 %0, %1, %2, %0 op_sel:[1,0,0] op_sel_hi:[1,1,1]"
        : "+v"(acc) : "v"(wt), "v"(x));
}
__device__ __forceinline__ void addw(unsigned& sw, unsigned wt) {
    asm("v_pk_add_f16 %0, %1, %0" : "+v"(sw) : "v"(wt));
}
// fast tanh: 1 - 2/(e^{2x}+1); both saturation limits exact.
__device__ __forceinline__ float fast_tanhf(float x) {
    float e2 = __expf(2.0f * x);
    return 1.0f - 2.0f * __builtin_amdgcn_rcpf(e2 + 1.0f);
}

// ---------------------------------------------------------------------------
// Single fused kernel, 512 blocks x 512 threads, 2 samples per block
// (waves 0-3 -> sample A, waves 4-7 -> sample B). One shared CSR build;
// fused per-half {nbr, wt} b64 entry stream (R15 structure, best at 24.5us).
// R18 CHANGE: the gather loop reads entry pairs as one 16B ds_read_b128
// (ewt rows are 16B aligned; scalar head/tail for odd ranges) — loop LDS
// instructions drop 4/iter -> 3.5/iter and loop control halves.
// LDS 75 KB -> 2 blocks/CU (= grid cap). Build scratch aliases x_sh.
// ---------------------------------------------------------------------------
__global__ __launch_bounds__(THREADS, 4) void rdgcn_fused_kernel(
    const float* __restrict__ x_in,      // [B, 24, 207]
    const float* __restrict__ w_react,   // [N_SLOTS, N_EDGES]
    const float* __restrict__ w_diff,    // [N_SLOTS, N_EDGES]
    const float* __restrict__ b_react,   // [N_SLOTS, N_NODES]
    const float* __restrict__ b_diff,    // [N_SLOTS, N_NODES]
    const float* __restrict__ w_self,    // [N_SLOTS, N_NODES]
    const int* __restrict__ ind,         // [B]
    const int* __restrict__ edge_index,  // [2, N_EDGES]
    float* __restrict__ out)             // [B, 207, 24]
{
    __shared__ unsigned x_sh[2][N_NODES * NPK];   // 19872 B (scratch aliases)
    __shared__ uint2    ewt_sh[2][TOT_ENT];       // 55104 B  (total 74976 B)

    const int tid  = threadIdx.x;
    const int h    = tid >> 8;          // sample half within block
    const int htid = tid & 255;
    const int lane = tid & 63;
    const int wid  = tid >> 6;
    const int bA   = blockIdx.x * 2;
    const int b    = bA + h;            // this thread's sample
    const int sA   = ind[bA];
    const int sB   = ind[bA + 1];
    const int s    = h ? sB : sA;

    // ---- issue x loads FIRST: HBM latency hides under the build ----
    float r[L_DIM];
    if (htid < N_NODES) {
        const float* xg = x_in + (size_t)b * (L_DIM * N_NODES);
        #pragma unroll
        for (int l = 0; l < L_DIM; ++l) r[l] = xg[l * N_NODES + htid];
    }

    // ---- build scratch aliased over x_sh (901 ints < 4968 available) ----
    int* cnt_s  = (int*)x_sh;           // [208]
    int* cur_s  = cnt_s + 208;          // [208]
    int* off_s  = cur_s + 208;          // [209]
    int* perm_s = off_s + 209;          // [208]
    int* dcur_s = perm_s + 208;         // [64]
    int* wsum_s = dcur_s + 64;          // [4]

    if (tid < 208) cnt_s[tid] = 0;
    if (tid < 64)  dcur_s[tid] = 0;
    __syncthreads();

    // pass 1: degree count; cache edge endpoints in regs (<=4 per thread)
    int ei[4], ej[4];
    int ne = 0;
    for (int e = tid; e < N_EDGES; e += THREADS) {
        int i = edge_index[e];
        int j = edge_index[N_EDGES + e];
        ei[ne] = i; ej[ne] = j; ++ne;
        atomicAdd(&cnt_s[i], 1);
        atomicAdd(&cnt_s[j], 1);
    }
    __syncthreads();

    // exclusive degree scan over slots 0..255 (waves 0-3, uniform branch)
    const int deg  = (tid < N_NODES) ? cnt_s[tid] : 0;
    const int dcap = deg > 63 ? 63 : deg;
    int xs = deg;
    if (tid < 256) {
        #pragma unroll
        for (int sft = 1; sft < 64; sft <<= 1) {
            int t = __shfl_up(xs, sft, 64);
            if (lane >= sft) xs += t;
        }
        if (lane == 63) wsum_s[wid] = xs;
    }
    if (tid < N_NODES) atomicAdd(&dcur_s[dcap], 1);
    __syncthreads();

    int base = 0;
    if (tid < 256) { for (int i = 0; i < wid; ++i) base += wsum_s[i]; }
    const int excl = base + xs - deg;
    if (tid < N_NODES) { off_s[tid] = excl; cur_s[tid] = excl; }
    if (tid == 255)    off_s[N_NODES] = base + xs;

    // descending-degree exclusive offsets for the counting sort
    if (tid < 64) {
        int hg = dcur_s[63 - tid];
        int ys = hg;
        #pragma unroll
        for (int sft = 1; sft < 64; sft <<= 1) {
            int t = __shfl_up(ys, sft, 64);
            if (lane >= sft) ys += t;
        }
        __syncthreads();                 // all reads of dcur done
        dcur_s[63 - tid] = ys - hg;
    } else {
        __syncthreads();
    }
    __syncthreads();

    if (tid < N_NODES) {
        int p = atomicAdd(&dcur_s[dcap], 1);
        perm_s[p] = tid;
    }
    // pass 2: place entries WITH both halves' packed weights (coalesced
    // weight reads, exactly once per edge; fused {nbr, wt} b64 writes)
    {
        const float* wrgA = w_react + (size_t)sA * N_EDGES;
        const float* wdgA = w_diff  + (size_t)sA * N_EDGES;
        const float* wrgB = w_react + (size_t)sB * N_EDGES;
        const float* wdgB = w_diff  + (size_t)sB * N_EDGES;
        for (int q = 0; q < ne; ++q) {
            const int e = tid + q * THREADS;
            const unsigned wtA = pkrtz(wrgA[e], wdgA[e]);
            const unsigned wtB = pkrtz(wrgB[e], wdgB[e]);
            const int i = ei[q], j = ej[q];
            int pi = atomicAdd(&cur_s[i], 1);
            ewt_sh[0][pi] = make_uint2((unsigned)j, wtA);
            ewt_sh[1][pi] = make_uint2((unsigned)j, wtB);
            int pj = atomicAdd(&cur_s[j], 1);
            ewt_sh[0][pj] = make_uint2((unsigned)i, wtA);
            ewt_sh[1][pj] = make_uint2((unsigned)i, wtB);
        }
    }
    __syncthreads();

    // consume scratch into registers before x staging overwrites it
    int w = 0, beg = 0, end = 0;
    if (htid < N_NODES) {
        w   = perm_s[htid];
        beg = off_s[w];
        end = off_s[w + 1];
    }
    __syncthreads();   // scratch reads complete; x_sh region free

    float br = 0.f, bd = 0.f, wsl = 0.f;
    if (htid < N_NODES) {
        br  = b_react[s * N_NODES + w];
        bd  = b_diff [s * N_NODES + w];
        wsl = w_self [s * N_NODES + w];
        // pack the (long-arrived) x row, write 3 x b128
        unsigned p[NPK];
        #pragma unroll
        for (int i = 0; i < NPK; ++i) p[i] = pkrtz(r[2*i], r[2*i+1]);
        uint4* dst = reinterpret_cast<uint4*>(&x_sh[h][htid * NPK]);
        dst[0] = make_uint4(p[0], p[1], p[2],  p[3]);
        dst[1] = make_uint4(p[4], p[5], p[6],  p[7]);
        dst[2] = make_uint4(p[8], p[9], p[10], p[11]);
    }
    __syncthreads();

    if (htid >= N_NODES) return;

    unsigned accr[NPK] = {0,0,0,0,0,0,0,0,0,0,0,0};   // f16x2 (reaction)
    unsigned accd[NPK] = {0,0,0,0,0,0,0,0,0,0,0,0};   // f16x2 (diffusion)
    unsigned sw = 0;                    // f16x2 (d_r, d_d) degree sums

    const uint2*    ew  = ewt_sh[h];
    const unsigned* xsh = x_sh[h];

    auto proc = [&](unsigned nbr, unsigned wt) {
        const uint4* xr = reinterpret_cast<const uint4*>(&xsh[nbr * NPK]);
        const uint4 qa = xr[0], qb = xr[1], qc = xr[2];
        addw(sw, wt);
        fma_lo(accr[0],  wt, qa.x);   fma_hi(accd[0],  wt, qa.x);
        fma_lo(accr[1],  wt, qa.y);   fma_hi(accd[1],  wt, qa.y);
        fma_lo(accr[2],  wt, qa.z);   fma_hi(accd[2],  wt, qa.z);
        fma_lo(accr[3],  wt, qa.w);   fma_hi(accd[3],  wt, qa.w);
        fma_lo(accr[4],  wt, qb.x);   fma_hi(accd[4],  wt, qb.x);
        fma_lo(accr[5],  wt, qb.y);   fma_hi(accd[5],  wt, qb.y);
        fma_lo(accr[6],  wt, qb.z);   fma_hi(accd[6],  wt, qb.z);
        fma_lo(accr[7],  wt, qb.w);   fma_hi(accd[7],  wt, qb.w);
        fma_lo(accr[8],  wt, qc.x);   fma_hi(accd[8],  wt, qc.x);
        fma_lo(accr[9],  wt, qc.y);   fma_hi(accd[9],  wt, qc.y);
        fma_lo(accr[10], wt, qc.z);   fma_hi(accd[10], wt, qc.z);
        fma_lo(accr[11], wt, qc.w);   fma_hi(accd[11], wt, qc.w);
    };

    int k = beg;
    if (k < end && (k & 1)) {           // odd head: single b64
        const uint2 q = ew[k];
        proc(q.x, q.y);
        ++k;
    }
    for (; k + 1 < end; k += 2) {       // paired: one b128 = two entries
        const uint4 q2 = *reinterpret_cast<const uint4*>(&ew[k]);
        proc(q2.x, q2.y);
        proc(q2.z, q2.w);
    }
    if (k < end) {                      // tail: single b64
        const uint2 q = ew[k];
        proc(q.x, q.y);
    }

    const f32x2 sw2 = h2f(sw);
    const float swr = sw2.x, swd = sw2.y;

    const uint4* xw = reinterpret_cast<const uint4*>(&xsh[w * NPK]);
    const uint4 r0 = xw[0], r1 = xw[1], r2 = xw[2];
    const unsigned own[NPK] = { r0.x, r0.y, r0.z, r0.w,
                                r1.x, r1.y, r1.z, r1.w,
                                r2.x, r2.y, r2.z, r2.w };

    float o[L_DIM];
    #pragma unroll
    for (int i = 0; i < NPK; ++i) {
        const f32x2 xv = h2f(own[i]);
        const f32x2 ar = h2f(accr[i]);
        const f32x2 ad = h2f(accd[i]);
        {
            float re = fmaf(swr, xv.x,  ar.x) + br;
            float di = fmaf(swd, xv.x, -ad.x) + bd;
            o[2*i]   = fast_tanhf(re) + di + fmaf(xv.x, wsl, xv.x);
        }
        {
            float re = fmaf(swr, xv.y,  ar.y) + br;
            float di = fmaf(swd, xv.y, -ad.y) + bd;
            o[2*i+1] = fast_tanhf(re) + di + fmaf(xv.y, wsl, xv.y);
        }
    }
    float* op = out + (size_t)b * (N_NODES * L_DIM) + (size_t)w * L_DIM;
    reinterpret_cast<float4*>(op)[0] = make_float4(o[0],  o[1],  o[2],  o[3]);
    reinterpret_cast<float4*>(op)[1] = make_float4(o[4],  o[5],  o[6],  o[7]);
    reinterpret_cast<float4*>(op)[2] = make_float4(o[8],  o[9],  o[10], o[11]);
    reinterpret_cast<float4*>(op)[3] = make_float4(o[12], o[13], o[14], o[15]);
    reinterpret_cast<float4*>(op)[4] = make_float4(o[16], o[17], o[18], o[19]);
    reinterpret_cast<float4*>(op)[5] = make_float4(o[20], o[21], o[22], o[23]);
}

extern "C" void kernel_launch(void* const* d_in, const int* in_sizes, int n_in,
                              void* d_out, int out_size, void* d_ws, size_t ws_size,
                              hipStream_t stream) {
    const float* x_in     = (const float*)d_in[0];
    const float* w_react  = (const float*)d_in[1];
    const float* w_diff   = (const float*)d_in[2];
    const float* b_react  = (const float*)d_in[3];
    const float* b_diff   = (const float*)d_in[4];
    const float* w_self   = (const float*)d_in[5];
    const int*   ind      = (const int*)d_in[6];
    const int*   edge_idx = (const int*)d_in[7];
    float* out = (float*)d_out;

    const int B = in_sizes[6];   // 1024
    rdgcn_fused_kernel<<<B / 2, THREADS, 0, stream>>>(x_in, w_react, w_diff,
                                                      b_react, b_diff, w_self,
                                                      ind, edge_idx, out);
}